// Round 5
// baseline (341.533 us; speedup 1.0000x reference)
//
#include <hip/hip_runtime.h>
#include <hip/hip_fp16.h>
#include <math.h>

#define DIM 256
#define NHEAD 8
#define NLVL 4
#define NPT 4
#define HDIM 32
#define FFDIM 1024
#define BATCH 4
#define SEQ 5440
#define MTOK (BATCH * SEQ)   // 21760

typedef __attribute__((ext_vector_type(8))) short short8;
typedef __attribute__((ext_vector_type(4))) float f32x4;

__device__ __forceinline__ unsigned short f2bf(float f) {
    union { float f; unsigned int u; } x; x.f = f;
    unsigned int r = x.u + 0x7fffu + ((x.u >> 16) & 1u);
    return (unsigned short)(r >> 16);
}

// ---------------------------------------------------------------------------
// prep kernel: LN1 (blocks 0..MTOK/4-1) + weight transpose/convert (rest).
// LN1: q = LN(input)*w+b + pos -> bf16; also input_bf = bf16(input).
// wtprep: wts layout [wval 256x256][woff 256x256][wattn 128x256][wout 256x256]
//         [ffw1 1024x256][ffw2 256x1024], N-major K-contig bf16.
// ---------------------------------------------------------------------------
#define LN_BLOCKS (MTOK / 4)

__global__ __launch_bounds__(256) void prep_kernel(
    const float* __restrict__ input, const float* __restrict__ pos,
    const float* __restrict__ ln1_w, const float* __restrict__ ln1_b,
    unsigned short* __restrict__ q_bf, unsigned short* __restrict__ input_bf,
    const float* __restrict__ W_val, const float* __restrict__ W_off,
    const float* __restrict__ W_attn, const float* __restrict__ W_out,
    const float* __restrict__ ff_w1, const float* __restrict__ ff_w2,
    const float* __restrict__ b_off, const float* __restrict__ b_attn,
    unsigned short* __restrict__ wts, float* __restrict__ bcomb)
{
    if (blockIdx.x < LN_BLOCKS) {
        int wv = threadIdx.x >> 6, lane = threadIdx.x & 63;
        int token = blockIdx.x * 4 + wv;
        size_t base = (size_t)token * DIM + lane * 4;
        float4 v = *(const float4*)(input + base);
        float s  = v.x + v.y + v.z + v.w;
        float s2 = v.x * v.x + v.y * v.y + v.z * v.z + v.w * v.w;
        #pragma unroll
        for (int o = 1; o < 64; o <<= 1) {
            s  += __shfl_xor(s, o);
            s2 += __shfl_xor(s2, o);
        }
        float m  = s * (1.0f / DIM);
        float rs = rsqrtf(s2 * (1.0f / DIM) - m * m + 1e-5f);
        float4 w4 = *(const float4*)(ln1_w + lane * 4);
        float4 b4 = *(const float4*)(ln1_b + lane * 4);
        float4 p4 = *(const float4*)(pos + base);
        float4 r;
        r.x = (v.x - m) * rs * w4.x + b4.x + p4.x;
        r.y = (v.y - m) * rs * w4.y + b4.y + p4.y;
        r.z = (v.z - m) * rs * w4.z + b4.z + p4.z;
        r.w = (v.w - m) * rs * w4.w + b4.w + p4.w;
        ushort4 o4;
        o4.x = f2bf(r.x); o4.y = f2bf(r.y); o4.z = f2bf(r.z); o4.w = f2bf(r.w);
        *(ushort4*)(q_bf + base) = o4;
        ushort4 c;
        c.x = f2bf(v.x); c.y = f2bf(v.y); c.z = f2bf(v.z); c.w = f2bf(v.w);
        *(ushort4*)(input_bf + base) = c;
        return;
    }
    int bidx = blockIdx.x - LN_BLOCKS;
    int idx = bidx * 256 + threadIdx.x;
    if (bidx == 0 && threadIdx.x < 384) {
        bcomb[threadIdx.x] = (threadIdx.x < 256) ? b_off[threadIdx.x]
                                                 : b_attn[threadIdx.x - 256];
    }
    const float* W; int K, N, base;
    if      (idx < 65536)  { W = W_val;  K = 256;  N = 256;  base = 0; }
    else if (idx < 131072) { W = W_off;  K = 256;  N = 256;  base = 65536; }
    else if (idx < 163840) { W = W_attn; K = 256;  N = 128;  base = 131072; }
    else if (idx < 229376) { W = W_out;  K = 256;  N = 256;  base = 163840; }
    else if (idx < 491520) { W = ff_w1;  K = 256;  N = 1024; base = 229376; }
    else if (idx < 753664) { W = ff_w2;  K = 1024; N = 256;  base = 491520; }
    else return;
    int li = idx - base;
    int k = li % K;
    int n = li / K;
    wts[idx] = f2bf(W[(size_t)k * N + n]);
}

// ---------------------------------------------------------------------------
// Direct-load MFMA GEMM core: NO LDS, NO barriers. Both A and Bt are
// K-contig, so each lane loads its 16B fragment straight from global
// (lanes {m16,m16+16,m16+32,m16+48} form one 64B line -> coalesced).
// Software-pipelined one K-step (32) ahead. acc[i][j] holds rows
// i*16+m16, cols j*16+quad*4..+3 (swapped-operand layout).
// ---------------------------------------------------------------------------
__device__ __forceinline__ void gemm_core(
    const unsigned short* __restrict__ A,   // row base: (bm0+i*16+m16)*K
    const unsigned short* __restrict__ Bt,
    int bm0, int bn0, int wrow, int wcol, int K,
    int m16, int quad, f32x4 acc[4][4])
{
    const unsigned short* ap[4];
    const unsigned short* bp[4];
    #pragma unroll
    for (int i = 0; i < 4; i++)
        ap[i] = A + (size_t)(bm0 + wrow + i * 16 + m16) * K + quad * 8;
    #pragma unroll
    for (int j = 0; j < 4; j++)
        bp[j] = Bt + (size_t)(bn0 + wcol + j * 16 + m16) * K + quad * 8;

    short8 af[4], bf[4];
    #pragma unroll
    for (int i = 0; i < 4; i++) af[i] = *(const short8*)(ap[i]);
    #pragma unroll
    for (int j = 0; j < 4; j++) bf[j] = *(const short8*)(bp[j]);

    #pragma unroll 2
    for (int k0 = 0; k0 < K; k0 += 32) {
        short8 afn[4], bfn[4];
        if (k0 + 32 < K) {
            #pragma unroll
            for (int i = 0; i < 4; i++) afn[i] = *(const short8*)(ap[i] + k0 + 32);
            #pragma unroll
            for (int j = 0; j < 4; j++) bfn[j] = *(const short8*)(bp[j] + k0 + 32);
        }
        #pragma unroll
        for (int i = 0; i < 4; i++)
            #pragma unroll
            for (int j = 0; j < 4; j++)
                acc[i][j] = __builtin_amdgcn_mfma_f32_16x16x32_bf16(
                    bf[j], af[i], acc[i][j], 0, 0, 0);
        if (k0 + 32 < K) {
            #pragma unroll
            for (int i = 0; i < 4; i++) af[i] = afn[i];
            #pragma unroll
            for (int j = 0; j < 4; j++) bf[j] = bfn[j];
        }
    }
}

// ---------------------------------------------------------------------------
// General GEMM: 128x128 tile, 4 waves in 2x2 quadrants.
// OUT: 0=fp32, 1=bf16, 2=fp16.
// ---------------------------------------------------------------------------
template<int K, int OUT, int RELU, int HAS_RES>
__global__ __launch_bounds__(256) void gemm_direct(
    const unsigned short* __restrict__ A,
    const unsigned short* __restrict__ Bt,
    const float* __restrict__ bias,
    const float* __restrict__ res,
    void* __restrict__ Cout, int N)
{
    const int tid  = threadIdx.x;
    const int lane = tid & 63;
    const int wv   = tid >> 6;
    const int wr   = (wv >> 1) * 64;
    const int wc   = (wv & 1) * 64;
    const int m16  = lane & 15;
    const int quad = lane >> 4;
    const int bm0 = blockIdx.y * 128;
    const int bn0 = blockIdx.x * 128;

    f32x4 acc[4][4] = {};
    gemm_core(A, Bt, bm0, bn0, wr, wc, K, m16, quad, acc);

    float4 bias4[4];
    #pragma unroll
    for (int j = 0; j < 4; j++)
        bias4[j] = *(const float4*)(bias + bn0 + wc + j * 16 + quad * 4);

    #pragma unroll
    for (int i = 0; i < 4; i++) {
        int row = bm0 + wr + i * 16 + m16;
        #pragma unroll
        for (int j = 0; j < 4; j++) {
            int col = bn0 + wc + j * 16 + quad * 4;
            float v0 = acc[i][j][0] + bias4[j].x;
            float v1 = acc[i][j][1] + bias4[j].y;
            float v2 = acc[i][j][2] + bias4[j].z;
            float v3 = acc[i][j][3] + bias4[j].w;
            if (HAS_RES) {
                float4 rr = *(const float4*)(res + (size_t)row * N + col);
                v0 += rr.x; v1 += rr.y; v2 += rr.z; v3 += rr.w;
            }
            if (RELU) {
                v0 = fmaxf(v0, 0.0f); v1 = fmaxf(v1, 0.0f);
                v2 = fmaxf(v2, 0.0f); v3 = fmaxf(v3, 0.0f);
            }
            if (OUT == 0) {
                float4 o = {v0, v1, v2, v3};
                *(float4*)((float*)Cout + (size_t)row * N + col) = o;
            } else if (OUT == 1) {
                ushort4 o;
                o.x = f2bf(v0); o.y = f2bf(v1); o.z = f2bf(v2); o.w = f2bf(v3);
                *(ushort4*)((unsigned short*)Cout + (size_t)row * N + col) = o;
            } else {
                ushort4 o;
                o.x = __half_as_ushort(__float2half_rn(v0));
                o.y = __half_as_ushort(__float2half_rn(v1));
                o.z = __half_as_ushort(__float2half_rn(v2));
                o.w = __half_as_ushort(__float2half_rn(v3));
                *(ushort4*)((unsigned short*)Cout + (size_t)row * N + col) = o;
            }
        }
    }
}

// ---------------------------------------------------------------------------
// Dual GEMM launch: blockIdx.x<2 -> value = input_bf @ wval (N=256, fp16 out)
//                   else         -> oa   = q_bf @ [woff|wattn] (N=384, fp16)
// ---------------------------------------------------------------------------
__global__ __launch_bounds__(256) void gemm_dual(
    const unsigned short* __restrict__ A0, const unsigned short* __restrict__ B0,
    const float* __restrict__ bias0, unsigned short* __restrict__ C0,
    const unsigned short* __restrict__ A1, const unsigned short* __restrict__ B1,
    const float* __restrict__ bias1, unsigned short* __restrict__ C1)
{
    const unsigned short *A, *Bt; const float* bias; unsigned short* C;
    int N, bx;
    if (blockIdx.x < 2) { A = A0; Bt = B0; bias = bias0; C = C0; N = 256; bx = blockIdx.x; }
    else                { A = A1; Bt = B1; bias = bias1; C = C1; N = 384; bx = blockIdx.x - 2; }

    const int tid  = threadIdx.x;
    const int lane = tid & 63;
    const int wv   = tid >> 6;
    const int wr   = (wv >> 1) * 64;
    const int wc   = (wv & 1) * 64;
    const int m16  = lane & 15;
    const int quad = lane >> 4;
    const int bm0 = blockIdx.y * 128;
    const int bn0 = bx * 128;

    f32x4 acc[4][4] = {};
    gemm_core(A, Bt, bm0, bn0, wr, wc, 256, m16, quad, acc);

    float4 bias4[4];
    #pragma unroll
    for (int j = 0; j < 4; j++)
        bias4[j] = *(const float4*)(bias + bn0 + wc + j * 16 + quad * 4);

    #pragma unroll
    for (int i = 0; i < 4; i++) {
        int row = bm0 + wr + i * 16 + m16;
        #pragma unroll
        for (int j = 0; j < 4; j++) {
            int col = bn0 + wc + j * 16 + quad * 4;
            ushort4 o;
            o.x = __half_as_ushort(__float2half_rn(acc[i][j][0] + bias4[j].x));
            o.y = __half_as_ushort(__float2half_rn(acc[i][j][1] + bias4[j].y));
            o.z = __half_as_ushort(__float2half_rn(acc[i][j][2] + bias4[j].z));
            o.w = __half_as_ushort(__float2half_rn(acc[i][j][3] + bias4[j].w));
            *(ushort4*)(C + (size_t)row * N + col) = o;
        }
    }
}

// ---------------------------------------------------------------------------
// W_out GEMM + residual + LN2 fused. Tile 64 rows x 256 cols (full row in
// block; wave wv owns cols wv*64..+63, all 64 rows). Writes x (fp32) and
// y = LN2(x) (bf16).
// ---------------------------------------------------------------------------
__global__ __launch_bounds__(256) void gemm_ln_kernel(
    const unsigned short* __restrict__ A,    // samp bf16 (MTOK,256)
    const unsigned short* __restrict__ Bt,   // wout 256x256
    const float* __restrict__ bias,          // b_out
    const float* __restrict__ res,           // input fp32
    const float* __restrict__ lnw, const float* __restrict__ lnb,
    float* __restrict__ xout, unsigned short* __restrict__ ybf)
{
    const int tid  = threadIdx.x;
    const int lane = tid & 63;
    const int wv   = tid >> 6;
    const int m16  = lane & 15;
    const int quad = lane >> 4;
    const int bm0  = blockIdx.x * 64;
    const int N = 256;

    f32x4 acc[4][4] = {};
    gemm_core(A, Bt, bm0, 0, 0, wv * 64, 256, m16, quad, acc);

    float4 bias4[4], lw4[4], lb4[4];
    #pragma unroll
    for (int j = 0; j < 4; j++) {
        int col = wv * 64 + j * 16 + quad * 4;
        bias4[j] = *(const float4*)(bias + col);
        lw4[j]   = *(const float4*)(lnw + col);
        lb4[j]   = *(const float4*)(lnb + col);
    }

    float v[4][4][4];
    float s1[4], s2[4];
    #pragma unroll
    for (int i = 0; i < 4; i++) {
        int row = bm0 + i * 16 + m16;
        s1[i] = 0.0f; s2[i] = 0.0f;
        #pragma unroll
        for (int j = 0; j < 4; j++) {
            int col = wv * 64 + j * 16 + quad * 4;
            float4 rr = *(const float4*)(res + (size_t)row * N + col);
            float b0 = bias4[j].x, b1 = bias4[j].y, b2 = bias4[j].z, b3 = bias4[j].w;
            v[i][j][0] = acc[i][j][0] + b0 + rr.x;
            v[i][j][1] = acc[i][j][1] + b1 + rr.y;
            v[i][j][2] = acc[i][j][2] + b2 + rr.z;
            v[i][j][3] = acc[i][j][3] + b3 + rr.w;
            #pragma unroll
            for (int r = 0; r < 4; r++) {
                s1[i] += v[i][j][r];
                s2[i] += v[i][j][r] * v[i][j][r];
            }
        }
    }
    // reduce across quads (lanes m16 fixed, quad varies = xor 16,32)
    #pragma unroll
    for (int i = 0; i < 4; i++) {
        s1[i] += __shfl_xor(s1[i], 16); s1[i] += __shfl_xor(s1[i], 32);
        s2[i] += __shfl_xor(s2[i], 16); s2[i] += __shfl_xor(s2[i], 32);
    }
    __shared__ float p1[4][4][16], p2[4][4][16];   // [wave][i][m16]
    if (quad == 0) {
        #pragma unroll
        for (int i = 0; i < 4; i++) { p1[wv][i][m16] = s1[i]; p2[wv][i][m16] = s2[i]; }
    }
    __syncthreads();
    #pragma unroll
    for (int i = 0; i < 4; i++) {
        float S1 = p1[0][i][m16] + p1[1][i][m16] + p1[2][i][m16] + p1[3][i][m16];
        float S2 = p2[0][i][m16] + p2[1][i][m16] + p2[2][i][m16] + p2[3][i][m16];
        float m  = S1 * (1.0f / DIM);
        float rs = rsqrtf(S2 * (1.0f / DIM) - m * m + 1e-5f);
        int row = bm0 + i * 16 + m16;
        #pragma unroll
        for (int j = 0; j < 4; j++) {
            int col = wv * 64 + j * 16 + quad * 4;
            float4 xo = {v[i][j][0], v[i][j][1], v[i][j][2], v[i][j][3]};
            *(float4*)(xout + (size_t)row * N + col) = xo;
            ushort4 yo;
            yo.x = f2bf((v[i][j][0] - m) * rs * lw4[j].x + lb4[j].x);
            yo.y = f2bf((v[i][j][1] - m) * rs * lw4[j].y + lb4[j].y);
            yo.z = f2bf((v[i][j][2] - m) * rs * lw4[j].z + lb4[j].z);
            yo.w = f2bf((v[i][j][3] - m) * rs * lw4[j].w + lb4[j].w);
            *(ushort4*)(ybf + (size_t)row * N + col) = yo;
        }
    }
}

// ---------------------------------------------------------------------------
// MS-deformable sampling (oa now fp16). Block = 8 tokens.
// ---------------------------------------------------------------------------
__global__ __launch_bounds__(256) void msdeform_kernel(
    const unsigned short* __restrict__ value_h, // (B,SEQ,256) fp16
    const __half* __restrict__ oa,              // (MTOK,384) fp16: off|attn
    const float* __restrict__ ref,              // (MTOK,8)
    unsigned short* __restrict__ samp_out)      // (MTOK,256) bf16
{
    const int Hs[NLVL] = {64, 32, 16, 8};
    const int Ws[NLVL] = {64, 32, 16, 8};
    const int St[NLVL] = {0, 4096, 5120, 5376};

    const int t  = threadIdx.x;
    const int tt = t >> 5;
    const int rr = t & 31;
    const int h  = rr >> 2;
    const int q  = rr & 3;
    const int token = blockIdx.x * 8 + tt;
    const int b = token / SEQ;

    __shared__ float s_attn[8][8][17];
    __shared__ uint2 s_tab[8][8][65];

    const __half* oat = oa + (size_t)token * 384;
    {
        union { uint2 u; __half2 h[2]; } au;
        au.u = *(const uint2*)(oat + 256 + h * 16 + q * 4);
        s_attn[tt][h][q * 4 + 0] = __low2float(au.h[0]);
        s_attn[tt][h][q * 4 + 1] = __high2float(au.h[0]);
        s_attn[tt][h][q * 4 + 2] = __low2float(au.h[1]);
        s_attn[tt][h][q * 4 + 3] = __high2float(au.h[1]);
    }
    float ox_[4], oy_[4];
    {
        union { uint4 u; __half2 h[4]; } ou;
        ou.u = *(const uint4*)(oat + h * 32 + q * 8);
        #pragma unroll
        for (int p = 0; p < 4; p++) {
            ox_[p] = __low2float(ou.h[p]);
            oy_[p] = __high2float(ou.h[p]);
        }
    }
    float2 rf = *(const float2*)(ref + (size_t)token * 8 + q * 2);
    __syncthreads();

    float mx = -1e30f;
    #pragma unroll
    for (int i = 0; i < 16; i++) mx = fmaxf(mx, s_attn[tt][h][i]);
    float sum = 0.0f;
    #pragma unroll
    for (int i = 0; i < 16; i++) sum += __expf(s_attn[tt][h][i] - mx);
    float inv = 1.0f / sum;

    {
        const int Hl = Hs[q], Wl = Ws[q], s0 = St[q];
        const float fW = (float)Wl, fH = (float)Hl;
        #pragma unroll
        for (int p = 0; p < 4; p++) {
            float aw = __expf(s_attn[tt][h][q * 4 + p] - mx) * inv;
            float x = (rf.x + ox_[p] / fW) * fW - 0.5f;
            float y = (rf.y + oy_[p] / fH) * fH - 0.5f;
            float x0f = floorf(x), y0f = floorf(y);
            float wx1 = x - x0f, wy1 = y - y0f;
            float wx0 = 1.0f - wx1, wy0 = 1.0f - wy1;
            int x0 = (int)x0f, y0 = (int)y0f;
            #pragma unroll
            for (int cy = 0; cy < 2; cy++) {
                int yi = y0 + cy;
                bool vy = (yi >= 0) && (yi < Hl);
                int yc = min(max(yi, 0), Hl - 1);
                float wy = cy ? wy1 : wy0;
                #pragma unroll
                for (int cx = 0; cx < 2; cx++) {
                    int xi = x0 + cx;
                    bool vx = (xi >= 0) && (xi < Wl);
                    int xc = min(max(xi, 0), Wl - 1);
                    float w = aw * wy * (cx ? wx1 : wx0) * ((vx && vy) ? 1.0f : 0.0f);
                    unsigned int off = (unsigned int)(s0 + yc * Wl + xc) * 512u;
                    unsigned short hw = __half_as_ushort(__float2half_rn(w));
                    unsigned int wp = (unsigned int)hw | ((unsigned int)hw << 16);
                    s_tab[tt][h][(q * 4 + p) * 4 + cy * 2 + cx] = make_uint2(off, wp);
                }
            }
        }
    }
    __syncthreads();

    const char* vb = (const char*)value_h;
    unsigned int cbase = (unsigned int)(b * (SEQ * 512)) + h * 64 + q * 16;
    const uint2* tab = &s_tab[tt][h][0];

    __half2 z; { union { unsigned int u; __half2 h; } c; c.u = 0; z = c.h; }
    __half2 acc0 = z, acc1 = z, acc2 = z, acc3 = z;

    #pragma unroll 16
    for (int i = 0; i < 64; i++) {
        uint2 e = tab[i];
        uint4 vv = *(const uint4*)(vb + (cbase + e.x));
        union { unsigned int u; __half2 h; } wu; wu.u = e.y;
        union { uint4 u; __half2 h[4]; } vu; vu.u = vv;
        acc0 = __hfma2(vu.h[0], wu.h, acc0);
        acc1 = __hfma2(vu.h[1], wu.h, acc1);
        acc2 = __hfma2(vu.h[2], wu.h, acc2);
        acc3 = __hfma2(vu.h[3], wu.h, acc3);
    }

    uint4 o;
    o.x = (unsigned int)f2bf(__low2float(acc0)) | ((unsigned int)f2bf(__high2float(acc0)) << 16);
    o.y = (unsigned int)f2bf(__low2float(acc1)) | ((unsigned int)f2bf(__high2float(acc1)) << 16);
    o.z = (unsigned int)f2bf(__low2float(acc2)) | ((unsigned int)f2bf(__high2float(acc2)) << 16);
    o.w = (unsigned int)f2bf(__low2float(acc3)) | ((unsigned int)f2bf(__high2float(acc3)) << 16);
    *(uint4*)(samp_out + (size_t)token * 256 + h * 32 + q * 8) = o;
}

// ---------------------------------------------------------------------------
// Launch
// ---------------------------------------------------------------------------
extern "C" void kernel_launch(void* const* d_in, const int* in_sizes, int n_in,
                              void* d_out, int out_size, void* d_ws, size_t ws_size,
                              hipStream_t stream) {
    const float* input = (const float*)d_in[0];
    const float* pos   = (const float*)d_in[1];
    const float* ref   = (const float*)d_in[2];
    const float* ln1_w = (const float*)d_in[5];
    const float* ln1_b = (const float*)d_in[6];
    const float* W_off = (const float*)d_in[7];
    const float* b_off = (const float*)d_in[8];
    const float* W_attn = (const float*)d_in[9];
    const float* b_attn = (const float*)d_in[10];
    const float* W_val = (const float*)d_in[11];
    const float* b_val = (const float*)d_in[12];
    const float* W_out = (const float*)d_in[13];
    const float* b_out = (const float*)d_in[14];
    const float* ln2_w = (const float*)d_in[15];
    const float* ln2_b = (const float*)d_in[16];
    const float* ff_w1 = (const float*)d_in[17];
    const float* ff_b1 = (const float*)d_in[18];
    const float* ff_w2 = (const float*)d_in[19];
    const float* ff_b2 = (const float*)d_in[20];
    float* out = (float*)d_out;

    const size_t M = MTOK;
    float* ws = (float*)d_ws;

    // Workspace (float units):
    unsigned short* input_bf = (unsigned short*)(ws);              // M*128f
    unsigned short* y_bf     = input_bf;                           // reuse
    unsigned short* q_bf     = (unsigned short*)(ws + M * 128);    // M*128f
    unsigned short* samp_bf  = q_bf;                               // reuse
    __half* oa_h  = (__half*)(ws + M * 256);                       // M*192f
    float*  x_buf = ws + M * 448;                                  // M*256f
    unsigned short* val_h = (unsigned short*)(ws + M * 704);       // M*128f
    unsigned short* h_bf  = (unsigned short*)(ws + M * 832);       // M*512f
    unsigned short* wts   = (unsigned short*)(ws + M * 1344);      // 753664 us
    float* bcomb = (float*)(wts + 753664);                         // 384 f

    unsigned short* wval_t  = wts;
    unsigned short* woff_t  = wval_t  + 256 * 256;   // [woff|wattn], N=384
    unsigned short* wout_t  = woff_t  + 384 * 256;
    unsigned short* ffw1_t  = wout_t  + 256 * 256;
    unsigned short* ffw2_t  = ffw1_t  + 1024 * 256;

    dim3 blk(256);

    // 1) LN1 + weight prep (one launch)
    prep_kernel<<<dim3(LN_BLOCKS + 2944), blk, 0, stream>>>(
        input, pos, ln1_w, ln1_b, q_bf, input_bf,
        W_val, W_off, W_attn, W_out, ff_w1, ff_w2, b_off, b_attn, wts, bcomb);

    // 2) value (fp16) + oa (fp16) in one launch
    gemm_dual<<<dim3(5, M / 128), blk, 0, stream>>>(
        input_bf, wval_t, b_val, (unsigned short*)val_h,
        q_bf, woff_t, bcomb, (unsigned short*)oa_h);

    // 3) sampling -> samp (bf16)
    msdeform_kernel<<<dim3(M / 8), blk, 0, stream>>>(
        val_h, oa_h, ref, samp_bf);

    // 4) x = input + samp @ W_out + b_out ; y = LN2(x)  (fused)
    gemm_ln_kernel<<<dim3(M / 64), blk, 0, stream>>>(
        samp_bf, wout_t, b_out, input, ln2_w, ln2_b, x_buf, y_bf);

    // 5) h = relu(y @ ff_w1 + ff_b1) -> bf16
    gemm_direct<256, 1, 1, 0><<<dim3(8, M / 128), blk, 0, stream>>>(
        y_bf, ffw1_t, ff_b1, nullptr, h_bf, 1024);

    // 6) out = x + h @ ff_w2 + ff_b2 -> fp32
    gemm_direct<1024, 0, 0, 1><<<dim3(2, M / 128), blk, 0, stream>>>(
        h_bf, ffw2_t, ff_b2, x_buf, out, 256);
}

// Round 6
// 256.842 us; speedup vs baseline: 1.3297x; 1.3297x over previous
//
#include <hip/hip_runtime.h>
#include <hip/hip_fp16.h>
#include <math.h>

#define DIM 256
#define NHEAD 8
#define NLVL 4
#define NPT 4
#define HDIM 32
#define FFDIM 1024
#define BATCH 4
#define SEQ 5440
#define MTOK (BATCH * SEQ)   // 21760

typedef __attribute__((ext_vector_type(8))) short short8;
typedef __attribute__((ext_vector_type(4))) float f32x4;

__device__ __forceinline__ unsigned short f2bf(float f) {
    union { float f; unsigned int u; } x; x.f = f;
    unsigned int r = x.u + 0x7fffu + ((x.u >> 16) & 1u);
    return (unsigned short)(r >> 16);
}

// async global->LDS, 16 B per lane. LDS dest must be wave-base + lane*16.
__device__ __forceinline__ void gll16(const unsigned short* g, unsigned short* l) {
    __builtin_amdgcn_global_load_lds(
        (const __attribute__((address_space(1))) void*)g,
        (__attribute__((address_space(3))) void*)l,
        16, 0, 0);
}

// ---------------------------------------------------------------------------
// prep kernel: LN1 (blocks 0..MTOK/4-1) + weight transpose/convert (rest).
// ---------------------------------------------------------------------------
#define LN_BLOCKS (MTOK / 4)

__global__ __launch_bounds__(256) void prep_kernel(
    const float* __restrict__ input, const float* __restrict__ pos,
    const float* __restrict__ ln1_w, const float* __restrict__ ln1_b,
    unsigned short* __restrict__ q_bf, unsigned short* __restrict__ input_bf,
    const float* __restrict__ W_val, const float* __restrict__ W_off,
    const float* __restrict__ W_attn, const float* __restrict__ W_out,
    const float* __restrict__ ff_w1, const float* __restrict__ ff_w2,
    const float* __restrict__ b_off, const float* __restrict__ b_attn,
    unsigned short* __restrict__ wts, float* __restrict__ bcomb)
{
    if (blockIdx.x < LN_BLOCKS) {
        int wv = threadIdx.x >> 6, lane = threadIdx.x & 63;
        int token = blockIdx.x * 4 + wv;
        size_t base = (size_t)token * DIM + lane * 4;
        float4 v = *(const float4*)(input + base);
        float s  = v.x + v.y + v.z + v.w;
        float s2 = v.x * v.x + v.y * v.y + v.z * v.z + v.w * v.w;
        #pragma unroll
        for (int o = 1; o < 64; o <<= 1) {
            s  += __shfl_xor(s, o);
            s2 += __shfl_xor(s2, o);
        }
        float m  = s * (1.0f / DIM);
        float rs = rsqrtf(s2 * (1.0f / DIM) - m * m + 1e-5f);
        float4 w4 = *(const float4*)(ln1_w + lane * 4);
        float4 b4 = *(const float4*)(ln1_b + lane * 4);
        float4 p4 = *(const float4*)(pos + base);
        float4 r;
        r.x = (v.x - m) * rs * w4.x + b4.x + p4.x;
        r.y = (v.y - m) * rs * w4.y + b4.y + p4.y;
        r.z = (v.z - m) * rs * w4.z + b4.z + p4.z;
        r.w = (v.w - m) * rs * w4.w + b4.w + p4.w;
        ushort4 o4;
        o4.x = f2bf(r.x); o4.y = f2bf(r.y); o4.z = f2bf(r.z); o4.w = f2bf(r.w);
        *(ushort4*)(q_bf + base) = o4;
        ushort4 c;
        c.x = f2bf(v.x); c.y = f2bf(v.y); c.z = f2bf(v.z); c.w = f2bf(v.w);
        *(ushort4*)(input_bf + base) = c;
        return;
    }
    int bidx = blockIdx.x - LN_BLOCKS;
    int idx = bidx * 256 + threadIdx.x;
    if (bidx == 0 && threadIdx.x < 384) {
        bcomb[threadIdx.x] = (threadIdx.x < 256) ? b_off[threadIdx.x]
                                                 : b_attn[threadIdx.x - 256];
    }
    const float* W; int K, N, base;
    if      (idx < 65536)  { W = W_val;  K = 256;  N = 256;  base = 0; }
    else if (idx < 131072) { W = W_off;  K = 256;  N = 256;  base = 65536; }
    else if (idx < 163840) { W = W_attn; K = 256;  N = 128;  base = 131072; }
    else if (idx < 229376) { W = W_out;  K = 256;  N = 256;  base = 163840; }
    else if (idx < 491520) { W = ff_w1;  K = 256;  N = 1024; base = 229376; }
    else if (idx < 753664) { W = ff_w2;  K = 1024; N = 256;  base = 491520; }
    else return;
    int li = idx - base;
    int k = li % K;
    int n = li / K;
    wts[idx] = f2bf(W[(size_t)k * N + n]);
}

// ---------------------------------------------------------------------------
// LDS-staged 128x128 MFMA core (round-4-verified structure).
// 4 waves in 2x2 quadrants of 64x64. acc[i][j]: rows i*16+m16 (+wr),
// cols j*16+quad*4..+3 (+wc) [swapped-operand layout].
// ---------------------------------------------------------------------------
__device__ __forceinline__ void core128(
    const unsigned short* __restrict__ A, const unsigned short* __restrict__ Bt,
    int K, int bm0, int bn0,
    unsigned short* As, unsigned short* Bs, int tid, f32x4 acc[4][4])
{
    const int lane = tid & 63;
    const int wv   = tid >> 6;
    const int wr   = (wv >> 1) * 64;
    const int wc   = (wv & 1) * 64;
    const int m16  = lane & 15;
    const int quad = lane >> 4;
    const int e0 = wv * 1024 + lane * 8;
    const int e1 = e0 + 512;
    const int r0 = e0 >> 5, c0 = e0 & 31;
    const int r1 = e1 >> 5, c1 = e1 & 31;

    for (int k0 = 0; k0 < K; k0 += 32) {
        if (k0) __syncthreads();
        gll16(A  + (size_t)(bm0 + r0) * K + k0 + c0, As + e0);
        gll16(A  + (size_t)(bm0 + r1) * K + k0 + c1, As + e1);
        gll16(Bt + (size_t)(bn0 + r0) * K + k0 + c0, Bs + e0);
        gll16(Bt + (size_t)(bn0 + r1) * K + k0 + c1, Bs + e1);
        __syncthreads();

        short8 af[4], bf[4];
        #pragma unroll
        for (int i = 0; i < 4; i++)
            af[i] = *(const short8*)&As[(wr + i * 16 + m16) * 32 + quad * 8];
        #pragma unroll
        for (int j = 0; j < 4; j++)
            bf[j] = *(const short8*)&Bs[(wc + j * 16 + m16) * 32 + quad * 8];

        #pragma unroll
        for (int i = 0; i < 4; i++)
            #pragma unroll
            for (int j = 0; j < 4; j++)
                acc[i][j] = __builtin_amdgcn_mfma_f32_16x16x32_bf16(
                    bf[j], af[i], acc[i][j], 0, 0, 0);
    }
}

// ---------------------------------------------------------------------------
// General 128x128 GEMM. OUT: 0=fp32, 1=bf16, 2=fp16.
// ---------------------------------------------------------------------------
template<int K, int OUT, int RELU, int HAS_RES>
__global__ __launch_bounds__(256) void gemm128(
    const unsigned short* __restrict__ A,
    const unsigned short* __restrict__ Bt,
    const float* __restrict__ bias,
    const float* __restrict__ res,
    void* __restrict__ Cout, int N)
{
    __shared__ __align__(16) unsigned short As[128 * 32];
    __shared__ __align__(16) unsigned short Bs[128 * 32];

    const int tid  = threadIdx.x;
    const int lane = tid & 63;
    const int wv   = tid >> 6;
    const int wr   = (wv >> 1) * 64;
    const int wc   = (wv & 1) * 64;
    const int m16  = lane & 15;
    const int quad = lane >> 4;
    const int bm0 = blockIdx.y * 128;
    const int bn0 = blockIdx.x * 128;

    f32x4 acc[4][4] = {};
    core128(A, Bt, K, bm0, bn0, As, Bs, tid, acc);

    float4 bias4[4];
    #pragma unroll
    for (int j = 0; j < 4; j++)
        bias4[j] = *(const float4*)(bias + bn0 + wc + j * 16 + quad * 4);

    #pragma unroll
    for (int i = 0; i < 4; i++) {
        int row = bm0 + wr + i * 16 + m16;
        #pragma unroll
        for (int j = 0; j < 4; j++) {
            int col = bn0 + wc + j * 16 + quad * 4;
            float v0 = acc[i][j][0] + bias4[j].x;
            float v1 = acc[i][j][1] + bias4[j].y;
            float v2 = acc[i][j][2] + bias4[j].z;
            float v3 = acc[i][j][3] + bias4[j].w;
            if (HAS_RES) {
                float4 rr = *(const float4*)(res + (size_t)row * N + col);
                v0 += rr.x; v1 += rr.y; v2 += rr.z; v3 += rr.w;
            }
            if (RELU) {
                v0 = fmaxf(v0, 0.0f); v1 = fmaxf(v1, 0.0f);
                v2 = fmaxf(v2, 0.0f); v3 = fmaxf(v3, 0.0f);
            }
            if (OUT == 0) {
                float4 o = {v0, v1, v2, v3};
                *(float4*)((float*)Cout + (size_t)row * N + col) = o;
            } else if (OUT == 1) {
                ushort4 o;
                o.x = f2bf(v0); o.y = f2bf(v1); o.z = f2bf(v2); o.w = f2bf(v3);
                *(ushort4*)((unsigned short*)Cout + (size_t)row * N + col) = o;
            } else {
                ushort4 o;
                o.x = __half_as_ushort(__float2half_rn(v0));
                o.y = __half_as_ushort(__float2half_rn(v1));
                o.z = __half_as_ushort(__float2half_rn(v2));
                o.w = __half_as_ushort(__float2half_rn(v3));
                *(ushort4*)((unsigned short*)Cout + (size_t)row * N + col) = o;
            }
        }
    }
}

// ---------------------------------------------------------------------------
// Dual GEMM: bx<2 -> value = input_bf @ wval (N=256); else oa (N=384).
// Both fp16 out, K=256, 128x128 LDS-staged.
// ---------------------------------------------------------------------------
__global__ __launch_bounds__(256) void gemm_dual(
    const unsigned short* __restrict__ A0, const unsigned short* __restrict__ B0,
    const float* __restrict__ bias0, unsigned short* __restrict__ C0,
    const unsigned short* __restrict__ A1, const unsigned short* __restrict__ B1,
    const float* __restrict__ bias1, unsigned short* __restrict__ C1)
{
    __shared__ __align__(16) unsigned short As[128 * 32];
    __shared__ __align__(16) unsigned short Bs[128 * 32];

    const unsigned short *A, *Bt; const float* bias; unsigned short* C;
    int N, bx;
    if (blockIdx.x < 2) { A = A0; Bt = B0; bias = bias0; C = C0; N = 256; bx = blockIdx.x; }
    else                { A = A1; Bt = B1; bias = bias1; C = C1; N = 384; bx = blockIdx.x - 2; }

    const int tid  = threadIdx.x;
    const int lane = tid & 63;
    const int wv   = tid >> 6;
    const int wr   = (wv >> 1) * 64;
    const int wc   = (wv & 1) * 64;
    const int m16  = lane & 15;
    const int quad = lane >> 4;
    const int bm0 = blockIdx.y * 128;
    const int bn0 = bx * 128;

    f32x4 acc[4][4] = {};
    core128(A, Bt, 256, bm0, bn0, As, Bs, tid, acc);

    float4 bias4[4];
    #pragma unroll
    for (int j = 0; j < 4; j++)
        bias4[j] = *(const float4*)(bias + bn0 + wc + j * 16 + quad * 4);

    #pragma unroll
    for (int i = 0; i < 4; i++) {
        int row = bm0 + wr + i * 16 + m16;
        #pragma unroll
        for (int j = 0; j < 4; j++) {
            int col = bn0 + wc + j * 16 + quad * 4;
            ushort4 o;
            o.x = __half_as_ushort(__float2half_rn(acc[i][j][0] + bias4[j].x));
            o.y = __half_as_ushort(__float2half_rn(acc[i][j][1] + bias4[j].y));
            o.z = __half_as_ushort(__float2half_rn(acc[i][j][2] + bias4[j].z));
            o.w = __half_as_ushort(__float2half_rn(acc[i][j][3] + bias4[j].w));
            *(ushort4*)(C + (size_t)row * N + col) = o;
        }
    }
}

// ---------------------------------------------------------------------------
// ffn2: 64x128 tile (4 waves in 2x2, 32x64 each), K=1024, LDS-staged,
// fp32 out + residual. Grid (N/128, M/64) = (2, 340) = 680 blocks.
// ---------------------------------------------------------------------------
__global__ __launch_bounds__(256) void gemm64_res(
    const unsigned short* __restrict__ A,    // h_bf (MTOK,1024)
    const unsigned short* __restrict__ Bt,   // ffw2 256x1024
    const float* __restrict__ bias,
    const float* __restrict__ res,           // x fp32
    float* __restrict__ Cout, int N)
{
    __shared__ __align__(16) unsigned short As[64 * 32];
    __shared__ __align__(16) unsigned short Bs[128 * 32];

    const int tid  = threadIdx.x;
    const int lane = tid & 63;
    const int wv   = tid >> 6;
    const int wr   = (wv >> 1) * 32;
    const int wc   = (wv & 1) * 64;
    const int m16  = lane & 15;
    const int quad = lane >> 4;
    const int bm0 = blockIdx.y * 64;
    const int bn0 = blockIdx.x * 128;
    const int K = 1024;

    const int eA = tid * 8;            // 2048 shorts = 64x32
    const int rA = tid >> 2, cA = (tid & 3) * 8;
    const int eB1 = eA + 2048;
    const int rB1 = rA + 64;

    f32x4 acc[2][4] = {};

    for (int k0 = 0; k0 < K; k0 += 32) {
        if (k0) __syncthreads();
        gll16(A  + (size_t)(bm0 + rA)  * K + k0 + cA, As + eA);
        gll16(Bt + (size_t)(bn0 + rA)  * K + k0 + cA, Bs + eA);
        gll16(Bt + (size_t)(bn0 + rB1) * K + k0 + cA, Bs + eB1);
        __syncthreads();

        short8 af[2], bf[4];
        #pragma unroll
        for (int i = 0; i < 2; i++)
            af[i] = *(const short8*)&As[(wr + i * 16 + m16) * 32 + quad * 8];
        #pragma unroll
        for (int j = 0; j < 4; j++)
            bf[j] = *(const short8*)&Bs[(wc + j * 16 + m16) * 32 + quad * 8];

        #pragma unroll
        for (int i = 0; i < 2; i++)
            #pragma unroll
            for (int j = 0; j < 4; j++)
                acc[i][j] = __builtin_amdgcn_mfma_f32_16x16x32_bf16(
                    bf[j], af[i], acc[i][j], 0, 0, 0);
    }

    float4 bias4[4];
    #pragma unroll
    for (int j = 0; j < 4; j++)
        bias4[j] = *(const float4*)(bias + bn0 + wc + j * 16 + quad * 4);

    #pragma unroll
    for (int i = 0; i < 2; i++) {
        int row = bm0 + wr + i * 16 + m16;
        #pragma unroll
        for (int j = 0; j < 4; j++) {
            int col = bn0 + wc + j * 16 + quad * 4;
            float4 rr = *(const float4*)(res + (size_t)row * N + col);
            float4 o;
            o.x = acc[i][j][0] + bias4[j].x + rr.x;
            o.y = acc[i][j][1] + bias4[j].y + rr.y;
            o.z = acc[i][j][2] + bias4[j].z + rr.z;
            o.w = acc[i][j][3] + bias4[j].w + rr.w;
            *(float4*)(Cout + (size_t)row * N + col) = o;
        }
    }
}

// ---------------------------------------------------------------------------
// W_out GEMM + residual + LN2 fused, LDS-staged. Tile 64 rows x 256 cols
// (full N in block; wave wv owns cols wv*64..+63, all 64 rows).
// Writes x (fp32) and y = LN2(x) (bf16). Grid M/64 = 340.
// ---------------------------------------------------------------------------
__global__ __launch_bounds__(256) void gemm_ln_kernel(
    const unsigned short* __restrict__ A,    // samp bf16 (MTOK,256)
    const unsigned short* __restrict__ Bt,   // wout 256x256
    const float* __restrict__ bias,          // b_out
    const float* __restrict__ res,           // input fp32
    const float* __restrict__ lnw, const float* __restrict__ lnb,
    float* __restrict__ xout, unsigned short* __restrict__ ybf)
{
    __shared__ __align__(16) unsigned short As[64 * 32];
    __shared__ __align__(16) unsigned short Bs[256 * 32];

    const int tid  = threadIdx.x;
    const int lane = tid & 63;
    const int wv   = tid >> 6;
    const int m16  = lane & 15;
    const int quad = lane >> 4;
    const int bm0  = blockIdx.x * 64;
    const int N = 256, K = 256;

    const int eA = tid * 8;
    const int rA = tid >> 2, cA = (tid & 3) * 8;

    f32x4 acc[4][4] = {};

    for (int k0 = 0; k0 < K; k0 += 32) {
        if (k0) __syncthreads();
        gll16(A + (size_t)(bm0 + rA) * K + k0 + cA, As + eA);
        #pragma unroll
        for (int s = 0; s < 4; s++)
            gll16(Bt + (size_t)(s * 64 + rA) * K + k0 + cA, Bs + s * 2048 + eA);
        __syncthreads();

        short8 af[4], bf[4];
        #pragma unroll
        for (int i = 0; i < 4; i++)
            af[i] = *(const short8*)&As[(i * 16 + m16) * 32 + quad * 8];
        #pragma unroll
        for (int j = 0; j < 4; j++)
            bf[j] = *(const short8*)&Bs[(wv * 64 + j * 16 + m16) * 32 + quad * 8];

        #pragma unroll
        for (int i = 0; i < 4; i++)
            #pragma unroll
            for (int j = 0; j < 4; j++)
                acc[i][j] = __builtin_amdgcn_mfma_f32_16x16x32_bf16(
                    bf[j], af[i], acc[i][j], 0, 0, 0);
    }

    float4 bias4[4], lw4[4], lb4[4];
    #pragma unroll
    for (int j = 0; j < 4; j++) {
        int col = wv * 64 + j * 16 + quad * 4;
        bias4[j] = *(const float4*)(bias + col);
        lw4[j]   = *(const float4*)(lnw + col);
        lb4[j]   = *(const float4*)(lnb + col);
    }

    float v[4][4][4];
    float s1[4], s2[4];
    #pragma unroll
    for (int i = 0; i < 4; i++) {
        int row = bm0 + i * 16 + m16;
        s1[i] = 0.0f; s2[i] = 0.0f;
        #pragma unroll
        for (int j = 0; j < 4; j++) {
            int col = wv * 64 + j * 16 + quad * 4;
            float4 rr = *(const float4*)(res + (size_t)row * N + col);
            v[i][j][0] = acc[i][j][0] + bias4[j].x + rr.x;
            v[i][j][1] = acc[i][j][1] + bias4[j].y + rr.y;
            v[i][j][2] = acc[i][j][2] + bias4[j].z + rr.z;
            v[i][j][3] = acc[i][j][3] + bias4[j].w + rr.w;
            #pragma unroll
            for (int r = 0; r < 4; r++) {
                s1[i] += v[i][j][r];
                s2[i] += v[i][j][r] * v[i][j][r];
            }
        }
    }
    #pragma unroll
    for (int i = 0; i < 4; i++) {
        s1[i] += __shfl_xor(s1[i], 16); s1[i] += __shfl_xor(s1[i], 32);
        s2[i] += __shfl_xor(s2[i], 16); s2[i] += __shfl_xor(s2[i], 32);
    }
    __syncthreads();   // Bs reads done; reuse LDS region for stats
    float* p1 = (float*)As;                 // [wave][i][m16] = 4*4*16
    float* p2 = p1 + 256;
    if (quad == 0) {
        #pragma unroll
        for (int i = 0; i < 4; i++) {
            p1[(wv * 4 + i) * 16 + m16] = s1[i];
            p2[(wv * 4 + i) * 16 + m16] = s2[i];
        }
    }
    __syncthreads();
    #pragma unroll
    for (int i = 0; i < 4; i++) {
        float S1 = p1[(0 * 4 + i) * 16 + m16] + p1[(1 * 4 + i) * 16 + m16]
                 + p1[(2 * 4 + i) * 16 + m16] + p1[(3 * 4 + i) * 16 + m16];
        float S2 = p2[(0 * 4 + i) * 16 + m16] + p2[(1 * 4 + i) * 16 + m16]
                 + p2[(2 * 4 + i) * 16 + m16] + p2[(3 * 4 + i) * 16 + m16];
        float m  = S1 * (1.0f / DIM);
        float rs = rsqrtf(S2 * (1.0f / DIM) - m * m + 1e-5f);
        int row = bm0 + i * 16 + m16;
        #pragma unroll
        for (int j = 0; j < 4; j++) {
            int col = wv * 64 + j * 16 + quad * 4;
            float4 xo = {v[i][j][0], v[i][j][1], v[i][j][2], v[i][j][3]};
            *(float4*)(xout + (size_t)row * N + col) = xo;
            ushort4 yo;
            yo.x = f2bf((v[i][j][0] - m) * rs * lw4[j].x + lb4[j].x);
            yo.y = f2bf((v[i][j][1] - m) * rs * lw4[j].y + lb4[j].y);
            yo.z = f2bf((v[i][j][2] - m) * rs * lw4[j].z + lb4[j].z);
            yo.w = f2bf((v[i][j][3] - m) * rs * lw4[j].w + lb4[j].w);
            *(ushort4*)(ybf + (size_t)row * N + col) = yo;
        }
    }
}

// ---------------------------------------------------------------------------
// MS-deformable sampling (fp16 value + fp16 oa). Block = 8 tokens.
// ---------------------------------------------------------------------------
__global__ __launch_bounds__(256) void msdeform_kernel(
    const unsigned short* __restrict__ value_h, // (B,SEQ,256) fp16
    const __half* __restrict__ oa,              // (MTOK,384) fp16: off|attn
    const float* __restrict__ ref,              // (MTOK,8)
    unsigned short* __restrict__ samp_out)      // (MTOK,256) bf16
{
    const int Hs[NLVL] = {64, 32, 16, 8};
    const int Ws[NLVL] = {64, 32, 16, 8};
    const int St[NLVL] = {0, 4096, 5120, 5376};

    const int t  = threadIdx.x;
    const int tt = t >> 5;
    const int rr = t & 31;
    const int h  = rr >> 2;
    const int q  = rr & 3;
    const int token = blockIdx.x * 8 + tt;
    const int b = token / SEQ;

    __shared__ float s_attn[8][8][17];
    __shared__ uint2 s_tab[8][8][65];

    const __half* oat = oa + (size_t)token * 384;
    {
        union { uint2 u; __half2 h[2]; } au;
        au.u = *(const uint2*)(oat + 256 + h * 16 + q * 4);
        s_attn[tt][h][q * 4 + 0] = __low2float(au.h[0]);
        s_attn[tt][h][q * 4 + 1] = __high2float(au.h[0]);
        s_attn[tt][h][q * 4 + 2] = __low2float(au.h[1]);
        s_attn[tt][h][q * 4 + 3] = __high2float(au.h[1]);
    }
    float ox_[4], oy_[4];
    {
        union { uint4 u; __half2 h[4]; } ou;
        ou.u = *(const uint4*)(oat + h * 32 + q * 8);
        #pragma unroll
        for (int p = 0; p < 4; p++) {
            ox_[p] = __low2float(ou.h[p]);
            oy_[p] = __high2float(ou.h[p]);
        }
    }
    float2 rf = *(const float2*)(ref + (size_t)token * 8 + q * 2);
    __syncthreads();

    float mx = -1e30f;
    #pragma unroll
    for (int i = 0; i < 16; i++) mx = fmaxf(mx, s_attn[tt][h][i]);
    float sum = 0.0f;
    #pragma unroll
    for (int i = 0; i < 16; i++) sum += __expf(s_attn[tt][h][i] - mx);
    float inv = 1.0f / sum;

    {
        const int Hl = Hs[q], Wl = Ws[q], s0 = St[q];
        const float fW = (float)Wl, fH = (float)Hl;
        #pragma unroll
        for (int p = 0; p < 4; p++) {
            float aw = __expf(s_attn[tt][h][q * 4 + p] - mx) * inv;
            float x = (rf.x + ox_[p] / fW) * fW - 0.5f;
            float y = (rf.y + oy_[p] / fH) * fH - 0.5f;
            float x0f = floorf(x), y0f = floorf(y);
            float wx1 = x - x0f, wy1 = y - y0f;
            float wx0 = 1.0f - wx1, wy0 = 1.0f - wy1;
            int x0 = (int)x0f, y0 = (int)y0f;
            #pragma unroll
            for (int cy = 0; cy < 2; cy++) {
                int yi = y0 + cy;
                bool vy = (yi >= 0) && (yi < Hl);
                int yc = min(max(yi, 0), Hl - 1);
                float wy = cy ? wy1 : wy0;
                #pragma unroll
                for (int cx = 0; cx < 2; cx++) {
                    int xi = x0 + cx;
                    bool vx = (xi >= 0) && (xi < Wl);
                    int xc = min(max(xi, 0), Wl - 1);
                    float w = aw * wy * (cx ? wx1 : wx0) * ((vx && vy) ? 1.0f : 0.0f);
                    unsigned int off = (unsigned int)(s0 + yc * Wl + xc) * 512u;
                    unsigned short hw = __half_as_ushort(__float2half_rn(w));
                    unsigned int wp = (unsigned int)hw | ((unsigned int)hw << 16);
                    s_tab[tt][h][(q * 4 + p) * 4 + cy * 2 + cx] = make_uint2(off, wp);
                }
            }
        }
    }
    __syncthreads();

    const char* vb = (const char*)value_h;
    unsigned int cbase = (unsigned int)(b * (SEQ * 512)) + h * 64 + q * 16;
    const uint2* tab = &s_tab[tt][h][0];

    __half2 z; { union { unsigned int u; __half2 h; } c; c.u = 0; z = c.h; }
    __half2 acc0 = z, acc1 = z, acc2 = z, acc3 = z;

    #pragma unroll 16
    for (int i = 0; i < 64; i++) {
        uint2 e = tab[i];
        uint4 vv = *(const uint4*)(vb + (cbase + e.x));
        union { unsigned int u; __half2 h; } wu; wu.u = e.y;
        union { uint4 u; __half2 h[4]; } vu; vu.u = vv;
        acc0 = __hfma2(vu.h[0], wu.h, acc0);
        acc1 = __hfma2(vu.h[1], wu.h, acc1);
        acc2 = __hfma2(vu.h[2], wu.h, acc2);
        acc3 = __hfma2(vu.h[3], wu.h, acc3);
    }

    uint4 o;
    o.x = (unsigned int)f2bf(__low2float(acc0)) | ((unsigned int)f2bf(__high2float(acc0)) << 16);
    o.y = (unsigned int)f2bf(__low2float(acc1)) | ((unsigned int)f2bf(__high2float(acc1)) << 16);
    o.z = (unsigned int)f2bf(__low2float(acc2)) | ((unsigned int)f2bf(__high2float(acc2)) << 16);
    o.w = (unsigned int)f2bf(__low2float(acc3)) | ((unsigned int)f2bf(__high2float(acc3)) << 16);
    *(uint4*)(samp_out + (size_t)token * 256 + h * 32 + q * 8) = o;
}

// ---------------------------------------------------------------------------
// Launch
// ---------------------------------------------------------------------------
extern "C" void kernel_launch(void* const* d_in, const int* in_sizes, int n_in,
                              void* d_out, int out_size, void* d_ws, size_t ws_size,
                              hipStream_t stream) {
    const float* input = (const float*)d_in[0];
    const float* pos   = (const float*)d_in[1];
    const float* ref   = (const float*)d_in[2];
    const float* ln1_w = (const float*)d_in[5];
    const float* ln1_b = (const float*)d_in[6];
    const float* W_off = (const float*)d_in[7];
    const float* b_off = (const float*)d_in[8];
    const float* W_attn = (const float*)d_in[9];
    const float* b_attn = (const float*)d_in[10];
    const float* W_val = (const float*)d_in[11];
    const float* b_val = (const float*)d_in[12];
    const float* W_out = (const float*)d_in[13];
    const float* b_out = (const float*)d_in[14];
    const float* ln2_w = (const float*)d_in[15];
    const float* ln2_b = (const float*)d_in[16];
    const float* ff_w1 = (const float*)d_in[17];
    const float* ff_b1 = (const float*)d_in[18];
    const float* ff_w2 = (const float*)d_in[19];
    const float* ff_b2 = (const float*)d_in[20];
    float* out = (float*)d_out;

    const size_t M = MTOK;
    float* ws = (float*)d_ws;

    // Workspace (float units):
    unsigned short* input_bf = (unsigned short*)(ws);              // M*128f
    unsigned short* y_bf     = input_bf;                           // reuse
    unsigned short* q_bf     = (unsigned short*)(ws + M * 128);    // M*128f
    unsigned short* samp_bf  = q_bf;                               // reuse
    __half* oa_h  = (__half*)(ws + M * 256);                       // M*192f
    float*  x_buf = ws + M * 448;                                  // M*256f
    unsigned short* val_h = (unsigned short*)(ws + M * 704);       // M*128f
    unsigned short* h_bf  = (unsigned short*)(ws + M * 832);       // M*512f
    unsigned short* wts   = (unsigned short*)(ws + M * 1344);      // 753664 us
    float* bcomb = (float*)(wts + 753664);                         // 384 f

    unsigned short* wval_t  = wts;
    unsigned short* woff_t  = wval_t  + 256 * 256;   // [woff|wattn], N=384
    unsigned short* wout_t  = woff_t  + 384 * 256;
    unsigned short* ffw1_t  = wout_t  + 256 * 256;
    unsigned short* ffw2_t  = ffw1_t  + 1024 * 256;

    dim3 blk(256);

    // 1) LN1 + weight prep
    prep_kernel<<<dim3(LN_BLOCKS + 2944), blk, 0, stream>>>(
        input, pos, ln1_w, ln1_b, q_bf, input_bf,
        W_val, W_off, W_attn, W_out, ff_w1, ff_w2, b_off, b_attn, wts, bcomb);

    // 2) value (fp16) + oa (fp16)
    gemm_dual<<<dim3(5, M / 128), blk, 0, stream>>>(
        input_bf, wval_t, b_val, (unsigned short*)val_h,
        q_bf, woff_t, bcomb, (unsigned short*)oa_h);

    // 3) sampling -> samp (bf16)
    msdeform_kernel<<<dim3(M / 8), blk, 0, stream>>>(
        val_h, oa_h, ref, samp_bf);

    // 4) x = input + samp @ W_out + b_out ; y = LN2(x)
    gemm_ln_kernel<<<dim3(M / 64), blk, 0, stream>>>(
        samp_bf, wout_t, b_out, input, ln2_w, ln2_b, x_buf, y_bf);

    // 5) h = relu(y @ ff_w1 + ff_b1) -> bf16
    gemm128<256, 1, 1, 0><<<dim3(8, M / 128), blk, 0, stream>>>(
        y_bf, ffw1_t, ff_b1, nullptr, h_bf, 1024);

    // 6) out = x + h @ ff_w2 + ff_b2 -> fp32
    gemm64_res<<<dim3(2, M / 64), blk, 0, stream>>>(
        h_bf, ffw2_t, ff_b2, x_buf, out, 256);
}